// Round 1
// baseline (302.808 us; speedup 1.0000x reference)
//
#include <hip/hip_runtime.h>
#include <hip/hip_bf16.h>
#include <cstdint>

// AFT-Local, S=2048 B=4 D=1024 W=256.
// Math: num/den normalizers cancel; exp_pb = 1 + c (c=expm1(pos_bias), window j<=i-255, else 0)
//  => num = colsum(U) + C@U, den = colsum(E) + C@E, with U=exp(k)*v, E=exp(k).
// mask input (d_in[12]) is all-True -> no-op in the reference; ignored here.

typedef short short8 __attribute__((ext_vector_type(8)));
typedef float f32x4 __attribute__((ext_vector_type(4)));

#define S_LEN 2048
#define BATCH 4
#define DMODEL 1024
#define NBD 4096           // B*D
#define SBD 8388608        // S*B*D
#define DD 1048576         // D*D
#define SS 4194304         // S*S

__device__ __forceinline__ unsigned short f2bf(float f) {
  union { float f; unsigned int u; } x; x.f = f;
  unsigned int u = x.u;
  unsigned int r = u + 0x7fffu + ((u >> 16) & 1u);
  return (unsigned short)(r >> 16);
}
__device__ __forceinline__ float bf2f(unsigned short b) {
  union { unsigned int u; float f; } x; x.u = ((unsigned int)b) << 16;
  return x.f;
}

// ---------------- f32 -> bf16 convert (vector-4) ----------------
__global__ void k_cvt(const float* __restrict__ src, unsigned short* __restrict__ dst, int n) {
  int i = (blockIdx.x * blockDim.x + threadIdx.x) * 4;
  if (i >= n) return;
  float4 f = *(const float4*)(src + i);
  ushort4 o;
  o.x = f2bf(f.x); o.y = f2bf(f.y); o.z = f2bf(f.z); o.w = f2bf(f.w);
  *(ushort4*)(dst + i) = o;
}

// ---------------- C[i][j] = (i >= j+255) ? expm1(pos_bias) : 0 ----------------
__global__ void k_build_c(const float* __restrict__ pb, unsigned short* __restrict__ C) {
  int idx = blockIdx.x * blockDim.x + threadIdx.x;  // over S*S
  int i = idx >> 11;
  int j = idx & 2047;
  float v = (i >= j + 255) ? expm1f(pb[idx]) : 0.0f;
  C[idx] = f2bf(v);
}

// ---------------- E/U compute + transpose to Mt[n][j] + column totals ----------------
// kbf/vbf viewed as [2048][4096] (j-major, n=b*1024+d). Mt is [8192][2048]:
// rows [0,4096) = U^T, rows [4096,8192) = E^T. totals[0..4096)=sum U, [4096..8192)=sum E.
__global__ __launch_bounds__(256) void k_eu_transpose(
    const unsigned short* __restrict__ kbf, const unsigned short* __restrict__ vbf,
    unsigned short* __restrict__ Mt, float* __restrict__ totals) {
  __shared__ unsigned short Lu[64][65];
  __shared__ unsigned short Le[64][65];
  const int n0 = blockIdx.x * 64;
  const int j0 = blockIdx.y * 64;
  const int t = threadIdx.x;
  const int c = t & 63;   // column (n) offset
  const int jq = t >> 6;  // 0..3
  float ptu = 0.f, pte = 0.f;
#pragma unroll 4
  for (int s = 0; s < 16; ++s) {
    int jj = jq + s * 4;
    size_t g = (size_t)(j0 + jj) * NBD + n0 + c;
    float kv = bf2f(kbf[g]);
    float vv = bf2f(vbf[g]);
    float e = __expf(kv);
    float u = e * vv;
    Le[jj][c] = f2bf(e);
    Lu[jj][c] = f2bf(u);
    pte += e; ptu += u;
  }
  atomicAdd(&totals[n0 + c], ptu);
  atomicAdd(&totals[NBD + n0 + c], pte);
  __syncthreads();
  const int jj2 = t & 63;  // j offset (contiguous in Mt row)
  const int nq = t >> 6;
#pragma unroll 4
  for (int s = 0; s < 16; ++s) {
    int nn = nq + s * 4;
    Mt[(size_t)(n0 + nn) * S_LEN + j0 + jj2] = Lu[jj2][nn];
    Mt[(size_t)(NBD + n0 + nn) * S_LEN + j0 + jj2] = Le[jj2][nn];
  }
}

// ---------------- bf16 GEMM: out[row][col] = sum_k A[row][k] * Bt[col][k] ----------------
// 128x128 tile, 4 waves (each 64x64 of 4x4 16x16x32 MFMA frags), BK=32, global_load_lds w16.
// mode: 0 = +bias,sigmoid -> bf16 ; 1 = +bias -> bf16 ; 2 = raw -> bf16 ; 3 = +bias -> f32
// tri: if nonzero, k-tiles limited to 4*blockIdx.y (block-lower-triangular C@M).
__global__ __launch_bounds__(256) void k_gemm_bt(
    const unsigned short* __restrict__ A, const unsigned short* __restrict__ Bt,
    const float* __restrict__ bias, void* __restrict__ out,
    int M, int N, int K, int mode, int tri) {
  __shared__ __align__(16) unsigned short lab[128 * 32];
  __shared__ __align__(16) unsigned short lbb[128 * 32];
  const int tid = threadIdx.x;
  const int wave = tid >> 6, lane = tid & 63;
  const int mb = blockIdx.y, nb = blockIdx.x;
  const int m0 = mb * 128, n0 = nb * 128;
  const int l15 = lane & 15, lh = lane >> 4;
  const int wr = (wave >> 1) * 64, wc = (wave & 1) * 64;

  f32x4 acc[4][4];
#pragma unroll
  for (int i = 0; i < 4; ++i)
#pragma unroll
    for (int j = 0; j < 4; ++j)
      acc[i][j] = (f32x4){0.f, 0.f, 0.f, 0.f};

  const int nk = tri ? (4 * mb) : (K >> 5);
  const int srow = lane >> 2;          // 0..15 within segment
  const int scol = (lane & 3) * 8;     // k-element offset of this lane's 16B

  for (int kt = 0; kt < nk; ++kt) {
    const int k0 = kt * 32;
    if (kt) __syncthreads();
#pragma unroll
    for (int cdx = 0; cdx < 2; ++cdx) {
      const int seg = wave * 2 + cdx;
      const int row = seg * 16 + srow;
      __builtin_amdgcn_global_load_lds(
          (const __attribute__((address_space(1))) unsigned int*)(A + (size_t)(m0 + row) * K + k0 + scol),
          (__attribute__((address_space(3))) unsigned int*)&lab[seg * 512], 16, 0, 0);
      __builtin_amdgcn_global_load_lds(
          (const __attribute__((address_space(1))) unsigned int*)(Bt + (size_t)(n0 + row) * K + k0 + scol),
          (__attribute__((address_space(3))) unsigned int*)&lbb[seg * 512], 16, 0, 0);
    }
    __syncthreads();
    short8 af[4], bfr[4];
#pragma unroll
    for (int f = 0; f < 4; ++f)
      af[f] = *(const short8*)&lab[(wr + f * 16 + l15) * 32 + lh * 8];
#pragma unroll
    for (int f = 0; f < 4; ++f)
      bfr[f] = *(const short8*)&lbb[(wc + f * 16 + l15) * 32 + lh * 8];
#pragma unroll
    for (int i = 0; i < 4; ++i)
#pragma unroll
      for (int j = 0; j < 4; ++j)
        acc[i][j] = __builtin_amdgcn_mfma_f32_16x16x32_bf16(af[i], bfr[j], acc[i][j], 0, 0, 0);
  }

  // epilogue: C/D layout col = lane&15, row = (lane>>4)*4 + r  [HW-verified]
#pragma unroll
  for (int i = 0; i < 4; ++i)
#pragma unroll
    for (int j = 0; j < 4; ++j)
#pragma unroll
      for (int r = 0; r < 4; ++r) {
        const int row = m0 + wr + i * 16 + lh * 4 + r;
        const int col = n0 + wc + j * 16 + l15;
        float v = acc[i][j][r];
        if (mode == 0) {
          v += bias[col];
          v = 1.0f / (1.0f + __expf(-v));
          ((unsigned short*)out)[(size_t)row * N + col] = f2bf(v);
        } else if (mode == 1) {
          v += bias[col];
          ((unsigned short*)out)[(size_t)row * N + col] = f2bf(v);
        } else if (mode == 2) {
          ((unsigned short*)out)[(size_t)row * N + col] = f2bf(v);
        } else {
          v += bias[col];
          ((float*)out)[(size_t)row * N + col] = v;
        }
      }
}

// ---------------- y = sigmoid(q) * (tu+Zu)/(te+Ze) ----------------
__global__ void k_y(const unsigned short* __restrict__ sigq, const unsigned short* __restrict__ Z,
                    const float* __restrict__ totals, unsigned short* __restrict__ Y) {
  size_t idx = (size_t)blockIdx.x * blockDim.x + threadIdx.x;  // over S*B*D
  int i = (int)(idx >> 12);   // sequence index
  int n = (int)(idx & 4095);  // b*1024+d
  float zu = bf2f(Z[(size_t)i * 8192 + n]);
  float ze = bf2f(Z[(size_t)i * 8192 + NBD + n]);
  float num = totals[n] + zu;
  float den = totals[NBD + n] + ze;
  float y = bf2f(sigq[idx]) * num / den;
  Y[idx] = f2bf(y);
}

extern "C" void kernel_launch(void* const* d_in, const int* in_sizes, int n_in,
                              void* d_out, int out_size, void* d_ws, size_t ws_size,
                              hipStream_t stream) {
  const float* query   = (const float*)d_in[0];
  const float* key_in  = (const float*)d_in[1];
  const float* value   = (const float*)d_in[2];
  const float* Wq      = (const float*)d_in[3];
  const float* bq      = (const float*)d_in[4];
  const float* Wk      = (const float*)d_in[5];
  const float* bk      = (const float*)d_in[6];
  const float* Wv      = (const float*)d_in[7];
  const float* bv      = (const float*)d_in[8];
  const float* pos_bias= (const float*)d_in[9];
  const float* Wo      = (const float*)d_in[10];
  const float* bo      = (const float*)d_in[11];
  // d_in[12] = mask: all-True -> no-op in reference.
  float* out = (float*)d_out;

  char* wp = (char*)d_ws;
  auto alloc = [&](size_t bytes) -> char* {
    char* p = wp;
    wp += (bytes + 255) & ~(size_t)255;
    return p;
  };
  unsigned short* Xq  = (unsigned short*)alloc((size_t)SBD * 2);
  unsigned short* Xk  = (unsigned short*)alloc((size_t)SBD * 2);
  unsigned short* Xv  = (unsigned short*)alloc((size_t)SBD * 2);
  unsigned short* Wqb = (unsigned short*)alloc((size_t)DD * 2);
  unsigned short* Wkb = (unsigned short*)alloc((size_t)DD * 2);
  unsigned short* Wvb = (unsigned short*)alloc((size_t)DD * 2);
  unsigned short* Wob = (unsigned short*)alloc((size_t)DD * 2);
  unsigned short* Cb  = (unsigned short*)alloc((size_t)SS * 2);
  unsigned short* sigq= (unsigned short*)alloc((size_t)SBD * 2);
  unsigned short* kbf = (unsigned short*)alloc((size_t)SBD * 2);
  unsigned short* vbf = (unsigned short*)alloc((size_t)SBD * 2);
  unsigned short* Mt  = (unsigned short*)alloc((size_t)8192 * S_LEN * 2);
  float*          tot = (float*)alloc((size_t)8192 * 4);
  unsigned short* Zb  = (unsigned short*)alloc((size_t)S_LEN * 8192 * 2);
  unsigned short* Yb  = (unsigned short*)alloc((size_t)SBD * 2);

  // 1) convert inputs/weights to bf16
  k_cvt<<<SBD / 4 / 256, 256, 0, stream>>>(query,  Xq, SBD);
  k_cvt<<<SBD / 4 / 256, 256, 0, stream>>>(key_in, Xk, SBD);
  k_cvt<<<SBD / 4 / 256, 256, 0, stream>>>(value,  Xv, SBD);
  k_cvt<<<DD / 4 / 256, 256, 0, stream>>>(Wq, Wqb, DD);
  k_cvt<<<DD / 4 / 256, 256, 0, stream>>>(Wk, Wkb, DD);
  k_cvt<<<DD / 4 / 256, 256, 0, stream>>>(Wv, Wvb, DD);
  k_cvt<<<DD / 4 / 256, 256, 0, stream>>>(Wo, Wob, DD);

  // 2) windowed expm1 coefficient matrix
  k_build_c<<<SS / 256, 256, 0, stream>>>(pos_bias, Cb);

  // 3) projections: q (sigmoid fused), k, v    [8192,1024] @ [1024,1024]^T
  dim3 gp(DMODEL / 128, 8192 / 128);
  k_gemm_bt<<<gp, 256, 0, stream>>>(Xq, Wqb, bq, sigq, 8192, DMODEL, DMODEL, 0, 0);
  k_gemm_bt<<<gp, 256, 0, stream>>>(Xk, Wkb, bk, kbf,  8192, DMODEL, DMODEL, 1, 0);
  k_gemm_bt<<<gp, 256, 0, stream>>>(Xv, Wvb, bv, vbf,  8192, DMODEL, DMODEL, 1, 0);

  // 4) E/U + transpose + totals
  hipMemsetAsync(tot, 0, 8192 * sizeof(float), stream);
  dim3 ge(NBD / 64, S_LEN / 64);
  k_eu_transpose<<<ge, 256, 0, stream>>>(kbf, vbf, Mt, tot);

  // 5) Z = C @ [U|E]   [2048,2048] @ [2048,8192], block-lower-triangular
  dim3 gz(8192 / 128, S_LEN / 128);
  k_gemm_bt<<<gz, 256, 0, stream>>>(Cb, Mt, nullptr, Zb, S_LEN, 8192, S_LEN, 2, 1);

  // 6) y = sigmoid(q) * num/den
  k_y<<<SBD / 256, 256, 0, stream>>>(sigq, Zb, tot, Yb);

  // 7) out = Y @ Wo^T + bo  (f32 store)
  k_gemm_bt<<<gp, 256, 0, stream>>>(Yb, Wob, bo, out, 8192, DMODEL, DMODEL, 3, 0);
}

// Round 2
// 231.714 us; speedup vs baseline: 1.3068x; 1.3068x over previous
//
#include <hip/hip_runtime.h>
#include <hip/hip_bf16.h>
#include <cstdint>

// AFT-Local, S=2048 B=4 D=1024 W=256.
// num/den softmax normalizers cancel; exp_pb = 1 + c (c=expm1(pos_bias) inside window j<=i-255, else 0)
//  => num = colsum(U) + C@U, den = colsum(E) + C@E, with U=exp(k)*v, E=exp(k).
// mask input (d_in[12]) is all-True -> no-op in the reference; ignored here.

typedef short short8 __attribute__((ext_vector_type(8)));
typedef float f32x4 __attribute__((ext_vector_type(4)));

#define S_LEN 2048
#define NBD 4096           // B*D
#define SBD 8388608        // S*B*D
#define DD 1048576         // D*D
#define SS 4194304         // S*S

__device__ __forceinline__ unsigned short f2bf(float f) {
  union { float f; unsigned int u; } x; x.f = f;
  unsigned int u = x.u;
  unsigned int r = u + 0x7fffu + ((u >> 16) & 1u);
  return (unsigned short)(r >> 16);
}
__device__ __forceinline__ float bf2f(unsigned short b) {
  union { unsigned int u; float f; } x; x.u = ((unsigned int)b) << 16;
  return x.f;
}

// ---------------- fused f32 -> bf16 converts ----------------
__global__ void k_cvt3(const float* __restrict__ a, const float* __restrict__ b,
                       const float* __restrict__ c, unsigned short* __restrict__ oa,
                       unsigned short* __restrict__ ob, unsigned short* __restrict__ oc) {
  int i = (blockIdx.x * blockDim.x + threadIdx.x) * 4;  // over SBD
  float4 fa = *(const float4*)(a + i);
  float4 fb = *(const float4*)(b + i);
  float4 fc = *(const float4*)(c + i);
  ushort4 ua, ub, uc;
  ua.x = f2bf(fa.x); ua.y = f2bf(fa.y); ua.z = f2bf(fa.z); ua.w = f2bf(fa.w);
  ub.x = f2bf(fb.x); ub.y = f2bf(fb.y); ub.z = f2bf(fb.z); ub.w = f2bf(fb.w);
  uc.x = f2bf(fc.x); uc.y = f2bf(fc.y); uc.z = f2bf(fc.z); uc.w = f2bf(fc.w);
  *(ushort4*)(oa + i) = ua;
  *(ushort4*)(ob + i) = ub;
  *(ushort4*)(oc + i) = uc;
}

// 4 weight matrices: Wq,Wk,Wv into contiguous Wcat[3*DD], Wo into Wob.
__global__ void k_cvt4w(const float* __restrict__ wq, const float* __restrict__ wk,
                        const float* __restrict__ wv, const float* __restrict__ wo,
                        unsigned short* __restrict__ wcat, unsigned short* __restrict__ wob) {
  int i = (blockIdx.x * blockDim.x + threadIdx.x) * 4;  // over DD
  float4 fq = *(const float4*)(wq + i);
  float4 fk = *(const float4*)(wk + i);
  float4 fv = *(const float4*)(wv + i);
  float4 fo = *(const float4*)(wo + i);
  ushort4 u;
  u.x = f2bf(fq.x); u.y = f2bf(fq.y); u.z = f2bf(fq.z); u.w = f2bf(fq.w);
  *(ushort4*)(wcat + i) = u;
  u.x = f2bf(fk.x); u.y = f2bf(fk.y); u.z = f2bf(fk.z); u.w = f2bf(fk.w);
  *(ushort4*)(wcat + DD + i) = u;
  u.x = f2bf(fv.x); u.y = f2bf(fv.y); u.z = f2bf(fv.z); u.w = f2bf(fv.w);
  *(ushort4*)(wcat + 2 * DD + i) = u;
  u.x = f2bf(fo.x); u.y = f2bf(fo.y); u.z = f2bf(fo.z); u.w = f2bf(fo.w);
  *(ushort4*)(wob + i) = u;
}

// ---------------- C[i][j] = (i >= j+255) ? expm1(pos_bias) : 0 ----------------
__global__ void k_build_c(const float* __restrict__ pb, unsigned short* __restrict__ C) {
  int idx = blockIdx.x * blockDim.x + threadIdx.x;  // over S*S
  int i = idx >> 11;
  int j = idx & 2047;
  float v = (i >= j + 255) ? expm1f(pb[idx]) : 0.0f;
  C[idx] = f2bf(v);
}

// ---------------- E/U compute + transpose to Mt[n][j] + column totals ----------------
__global__ __launch_bounds__(256) void k_eu_transpose(
    const unsigned short* __restrict__ kbf, const unsigned short* __restrict__ vbf,
    unsigned short* __restrict__ Mt, float* __restrict__ totals) {
  __shared__ unsigned short Lu[64][65];
  __shared__ unsigned short Le[64][65];
  const int n0 = blockIdx.x * 64;
  const int j0 = blockIdx.y * 64;
  const int t = threadIdx.x;
  const int c = t & 63;
  const int jq = t >> 6;
  float ptu = 0.f, pte = 0.f;
#pragma unroll 4
  for (int s = 0; s < 16; ++s) {
    int jj = jq + s * 4;
    size_t g = (size_t)(j0 + jj) * NBD + n0 + c;
    float kv = bf2f(kbf[g]);
    float vv = bf2f(vbf[g]);
    float e = __expf(kv);
    float u = e * vv;
    Le[jj][c] = f2bf(e);
    Lu[jj][c] = f2bf(u);
    pte += e; ptu += u;
  }
  atomicAdd(&totals[n0 + c], ptu);
  atomicAdd(&totals[NBD + n0 + c], pte);
  __syncthreads();
  const int jj2 = t & 63;
  const int nq = t >> 6;
#pragma unroll 4
  for (int s = 0; s < 16; ++s) {
    int nn = nq + s * 4;
    Mt[(size_t)(n0 + nn) * S_LEN + j0 + jj2] = Lu[jj2][nn];
    Mt[(size_t)(NBD + n0 + nn) * S_LEN + j0 + jj2] = Le[jj2][nn];
  }
}

// ---------------- fused QKV GEMM: [8192,1024]x3 @ Wcat^T[3072,1024] ----------------
// 128x128 tile, block-uniform col range selects A/bias/out. grid (24, 64) = 1536 blocks.
__global__ __launch_bounds__(256) void k_gemm_qkv(
    const unsigned short* __restrict__ A0, const unsigned short* __restrict__ A1,
    const unsigned short* __restrict__ A2, const unsigned short* __restrict__ Wcat,
    const float* __restrict__ b0, const float* __restrict__ b1, const float* __restrict__ b2,
    unsigned short* __restrict__ o0, unsigned short* __restrict__ o1,
    unsigned short* __restrict__ o2) {
  __shared__ __align__(16) unsigned short lab[128 * 32];
  __shared__ __align__(16) unsigned short lbb[128 * 32];
  const int tid = threadIdx.x;
  const int wave = tid >> 6, lane = tid & 63;
  const int mb = blockIdx.y, nb = blockIdx.x;
  const int m0 = mb * 128, n0 = nb * 128;
  const int grp = nb >> 3;  // 0=q, 1=k, 2=v
  const unsigned short* A = grp == 0 ? A0 : (grp == 1 ? A1 : A2);
  const float* bias = grp == 0 ? b0 : (grp == 1 ? b1 : b2);
  unsigned short* out = grp == 0 ? o0 : (grp == 1 ? o1 : o2);
  const int l15 = lane & 15, lh = lane >> 4;
  const int wr = (wave >> 1) * 64, wc = (wave & 1) * 64;

  f32x4 acc[4][4];
#pragma unroll
  for (int i = 0; i < 4; ++i)
#pragma unroll
    for (int j = 0; j < 4; ++j)
      acc[i][j] = (f32x4){0.f, 0.f, 0.f, 0.f};

  const int srow = lane >> 2;
  const int scol = (lane & 3) * 8;

  for (int kt = 0; kt < 32; ++kt) {
    const int k0 = kt * 32;
    if (kt) __syncthreads();
#pragma unroll
    for (int cdx = 0; cdx < 2; ++cdx) {
      const int seg = wave * 2 + cdx;
      const int row = seg * 16 + srow;
      __builtin_amdgcn_global_load_lds(
          (const __attribute__((address_space(1))) unsigned int*)(A + (size_t)(m0 + row) * 1024 + k0 + scol),
          (__attribute__((address_space(3))) unsigned int*)&lab[seg * 512], 16, 0, 0);
      __builtin_amdgcn_global_load_lds(
          (const __attribute__((address_space(1))) unsigned int*)(Wcat + (size_t)(n0 + row) * 1024 + k0 + scol),
          (__attribute__((address_space(3))) unsigned int*)&lbb[seg * 512], 16, 0, 0);
    }
    __syncthreads();
    short8 af[4], bfr[4];
#pragma unroll
    for (int f = 0; f < 4; ++f)
      af[f] = *(const short8*)&lab[(wr + f * 16 + l15) * 32 + lh * 8];
#pragma unroll
    for (int f = 0; f < 4; ++f)
      bfr[f] = *(const short8*)&lbb[(wc + f * 16 + l15) * 32 + lh * 8];
#pragma unroll
    for (int i = 0; i < 4; ++i)
#pragma unroll
      for (int j = 0; j < 4; ++j)
        acc[i][j] = __builtin_amdgcn_mfma_f32_16x16x32_bf16(af[i], bfr[j], acc[i][j], 0, 0, 0);
  }

#pragma unroll
  for (int i = 0; i < 4; ++i)
#pragma unroll
    for (int j = 0; j < 4; ++j)
#pragma unroll
      for (int r = 0; r < 4; ++r) {
        const int row = m0 + wr + i * 16 + lh * 4 + r;
        const int col = (n0 + wc + j * 16 + l15) & 1023;  // local within 1024-wide output
        float v = acc[i][j][r] + bias[col];
        if (grp == 0) v = 1.0f / (1.0f + __expf(-v));
        out[(size_t)row * 1024 + col] = f2bf(v);
      }
}

// ---------------- triangular Z = C @ [U|E]^T-staged  (block-lower-triangular) ----------------
__global__ __launch_bounds__(256) void k_gemm_tri(
    const unsigned short* __restrict__ A, const unsigned short* __restrict__ Bt,
    unsigned short* __restrict__ out) {
  __shared__ __align__(16) unsigned short lab[128 * 32];
  __shared__ __align__(16) unsigned short lbb[128 * 32];
  const int tid = threadIdx.x;
  const int wave = tid >> 6, lane = tid & 63;
  const int mb = blockIdx.y, nb = blockIdx.x;
  const int m0 = mb * 128, n0 = nb * 128;
  const int l15 = lane & 15, lh = lane >> 4;
  const int wr = (wave >> 1) * 64, wc = (wave & 1) * 64;

  f32x4 acc[4][4];
#pragma unroll
  for (int i = 0; i < 4; ++i)
#pragma unroll
    for (int j = 0; j < 4; ++j)
      acc[i][j] = (f32x4){0.f, 0.f, 0.f, 0.f};

  // window j <= i-255: for row block mb, nonzero k-tiles are 0 .. 4*mb-4
  const int nk = mb > 0 ? 4 * mb - 3 : 0;
  const int srow = lane >> 2;
  const int scol = (lane & 3) * 8;

  for (int kt = 0; kt < nk; ++kt) {
    const int k0 = kt * 32;
    if (kt) __syncthreads();
#pragma unroll
    for (int cdx = 0; cdx < 2; ++cdx) {
      const int seg = wave * 2 + cdx;
      const int row = seg * 16 + srow;
      __builtin_amdgcn_global_load_lds(
          (const __attribute__((address_space(1))) unsigned int*)(A + (size_t)(m0 + row) * S_LEN + k0 + scol),
          (__attribute__((address_space(3))) unsigned int*)&lab[seg * 512], 16, 0, 0);
      __builtin_amdgcn_global_load_lds(
          (const __attribute__((address_space(1))) unsigned int*)(Bt + (size_t)(n0 + row) * S_LEN + k0 + scol),
          (__attribute__((address_space(3))) unsigned int*)&lbb[seg * 512], 16, 0, 0);
    }
    __syncthreads();
    short8 af[4], bfr[4];
#pragma unroll
    for (int f = 0; f < 4; ++f)
      af[f] = *(const short8*)&lab[(wr + f * 16 + l15) * 32 + lh * 8];
#pragma unroll
    for (int f = 0; f < 4; ++f)
      bfr[f] = *(const short8*)&lbb[(wc + f * 16 + l15) * 32 + lh * 8];
#pragma unroll
    for (int i = 0; i < 4; ++i)
#pragma unroll
      for (int j = 0; j < 4; ++j)
        acc[i][j] = __builtin_amdgcn_mfma_f32_16x16x32_bf16(af[i], bfr[j], acc[i][j], 0, 0, 0);
  }

#pragma unroll
  for (int i = 0; i < 4; ++i)
#pragma unroll
    for (int j = 0; j < 4; ++j)
#pragma unroll
      for (int r = 0; r < 4; ++r) {
        const int row = m0 + wr + i * 16 + lh * 4 + r;
        const int col = n0 + wc + j * 16 + l15;
        out[(size_t)row * 8192 + col] = f2bf(acc[i][j][r]);
      }
}

// ---------------- output GEMM: out = Y @ Wo^T + bo, 64x128 tile, f32 store ----------------
// grid (8, 128) = 1024 blocks. 4 waves: wr=(w>>1)*32 (2 frags), wc=(w&1)*64 (4 frags).
__global__ __launch_bounds__(256) void k_gemm_out64(
    const unsigned short* __restrict__ A, const unsigned short* __restrict__ Bt,
    const float* __restrict__ bias, float* __restrict__ out) {
  __shared__ __align__(16) unsigned short laa[64 * 32];
  __shared__ __align__(16) unsigned short lbb[128 * 32];
  const int tid = threadIdx.x;
  const int wave = tid >> 6, lane = tid & 63;
  const int mb = blockIdx.y, nb = blockIdx.x;
  const int m0 = mb * 64, n0 = nb * 128;
  const int l15 = lane & 15, lh = lane >> 4;
  const int wr = (wave >> 1) * 32, wc = (wave & 1) * 64;

  f32x4 acc[2][4];
#pragma unroll
  for (int i = 0; i < 2; ++i)
#pragma unroll
    for (int j = 0; j < 4; ++j)
      acc[i][j] = (f32x4){0.f, 0.f, 0.f, 0.f};

  const int srow = lane >> 2;
  const int scol = (lane & 3) * 8;

  for (int kt = 0; kt < 32; ++kt) {
    const int k0 = kt * 32;
    if (kt) __syncthreads();
    {
      const int row = wave * 16 + srow;  // A: 4 segs, one per wave
      __builtin_amdgcn_global_load_lds(
          (const __attribute__((address_space(1))) unsigned int*)(A + (size_t)(m0 + row) * 1024 + k0 + scol),
          (__attribute__((address_space(3))) unsigned int*)&laa[wave * 512], 16, 0, 0);
    }
#pragma unroll
    for (int cdx = 0; cdx < 2; ++cdx) {
      const int seg = wave * 2 + cdx;
      const int row = seg * 16 + srow;
      __builtin_amdgcn_global_load_lds(
          (const __attribute__((address_space(1))) unsigned int*)(Bt + (size_t)(n0 + row) * 1024 + k0 + scol),
          (__attribute__((address_space(3))) unsigned int*)&lbb[seg * 512], 16, 0, 0);
    }
    __syncthreads();
    short8 af[2], bfr[4];
#pragma unroll
    for (int f = 0; f < 2; ++f)
      af[f] = *(const short8*)&laa[(wr + f * 16 + l15) * 32 + lh * 8];
#pragma unroll
    for (int f = 0; f < 4; ++f)
      bfr[f] = *(const short8*)&lbb[(wc + f * 16 + l15) * 32 + lh * 8];
#pragma unroll
    for (int i = 0; i < 2; ++i)
#pragma unroll
      for (int j = 0; j < 4; ++j)
        acc[i][j] = __builtin_amdgcn_mfma_f32_16x16x32_bf16(af[i], bfr[j], acc[i][j], 0, 0, 0);
  }

#pragma unroll
  for (int i = 0; i < 2; ++i)
#pragma unroll
    for (int j = 0; j < 4; ++j)
#pragma unroll
      for (int r = 0; r < 4; ++r) {
        const int row = m0 + wr + i * 16 + lh * 4 + r;
        const int col = n0 + wc + j * 16 + l15;
        out[(size_t)row * 1024 + col] = acc[i][j][r] + bias[col];
      }
}

// ---------------- y = sigmoid(q) * (tu+Zu)/(te+Ze), vectorized x4 ----------------
__global__ void k_y(const unsigned short* __restrict__ sigq, const unsigned short* __restrict__ Z,
                    const float* __restrict__ totals, unsigned short* __restrict__ Y) {
  size_t idx = ((size_t)blockIdx.x * blockDim.x + threadIdx.x) * 4;  // over S*B*D
  int i = (int)(idx >> 12);
  int n = (int)(idx & 4095);
  ushort4 zu4 = *(const ushort4*)&Z[(size_t)i * 8192 + n];
  ushort4 ze4 = *(const ushort4*)&Z[(size_t)i * 8192 + NBD + n];
  ushort4 sq4 = *(const ushort4*)&sigq[idx];
  float4 tu = *(const float4*)&totals[n];
  float4 te = *(const float4*)&totals[NBD + n];
  ushort4 o;
  o.x = f2bf(bf2f(sq4.x) * (tu.x + bf2f(zu4.x)) / (te.x + bf2f(ze4.x)));
  o.y = f2bf(bf2f(sq4.y) * (tu.y + bf2f(zu4.y)) / (te.y + bf2f(ze4.y)));
  o.z = f2bf(bf2f(sq4.z) * (tu.z + bf2f(zu4.z)) / (te.z + bf2f(ze4.z)));
  o.w = f2bf(bf2f(sq4.w) * (tu.w + bf2f(zu4.w)) / (te.w + bf2f(ze4.w)));
  *(ushort4*)&Y[idx] = o;
}

extern "C" void kernel_launch(void* const* d_in, const int* in_sizes, int n_in,
                              void* d_out, int out_size, void* d_ws, size_t ws_size,
                              hipStream_t stream) {
  const float* query   = (const float*)d_in[0];
  const float* key_in  = (const float*)d_in[1];
  const float* value   = (const float*)d_in[2];
  const float* Wq      = (const float*)d_in[3];
  const float* bq      = (const float*)d_in[4];
  const float* Wk      = (const float*)d_in[5];
  const float* bk      = (const float*)d_in[6];
  const float* Wv      = (const float*)d_in[7];
  const float* bv      = (const float*)d_in[8];
  const float* pos_bias= (const float*)d_in[9];
  const float* Wo      = (const float*)d_in[10];
  const float* bo      = (const float*)d_in[11];
  float* out = (float*)d_out;

  char* wp = (char*)d_ws;
  auto alloc = [&](size_t bytes) -> char* {
    char* p = wp;
    wp += (bytes + 255) & ~(size_t)255;
    return p;
  };
  unsigned short* Xq   = (unsigned short*)alloc((size_t)SBD * 2);
  unsigned short* Xk   = (unsigned short*)alloc((size_t)SBD * 2);
  unsigned short* Xv   = (unsigned short*)alloc((size_t)SBD * 2);
  unsigned short* Wcat = (unsigned short*)alloc((size_t)3 * DD * 2);
  unsigned short* Wob  = (unsigned short*)alloc((size_t)DD * 2);
  unsigned short* Cb   = (unsigned short*)alloc((size_t)SS * 2);
  unsigned short* sigq = (unsigned short*)alloc((size_t)SBD * 2);
  unsigned short* kbf  = (unsigned short*)alloc((size_t)SBD * 2);
  unsigned short* vbf  = (unsigned short*)alloc((size_t)SBD * 2);
  unsigned short* Mt   = (unsigned short*)alloc((size_t)8192 * S_LEN * 2);
  float*          tot  = (float*)alloc((size_t)8192 * 4);
  unsigned short* Zb   = (unsigned short*)alloc((size_t)S_LEN * 8192 * 2);
  unsigned short* Yb   = (unsigned short*)alloc((size_t)SBD * 2);

  // 1) converts (2 launches)
  k_cvt3<<<SBD / 4 / 256, 256, 0, stream>>>(query, key_in, value, Xq, Xk, Xv);
  k_cvt4w<<<DD / 4 / 256, 256, 0, stream>>>(Wq, Wk, Wv, Wo, Wcat, Wob);

  // 2) windowed expm1 coefficient matrix
  k_build_c<<<SS / 256, 256, 0, stream>>>(pos_bias, Cb);

  // 3) fused QKV projection  [8192,1024]x3 @ [3072,1024]^T
  dim3 gq(3072 / 128, 8192 / 128);
  k_gemm_qkv<<<gq, 256, 0, stream>>>(Xq, Xk, Xv, Wcat, bq, bk, bv, sigq, kbf, vbf);

  // 4) E/U + transpose + totals
  hipMemsetAsync(tot, 0, 8192 * sizeof(float), stream);
  dim3 ge(NBD / 64, S_LEN / 64);
  k_eu_transpose<<<ge, 256, 0, stream>>>(kbf, vbf, Mt, tot);

  // 5) Z = C @ [U|E]  (block-lower-triangular)
  dim3 gz(8192 / 128, S_LEN / 128);
  k_gemm_tri<<<gz, 256, 0, stream>>>(Cb, Mt, Zb);

  // 6) y = sigmoid(q) * num/den
  k_y<<<SBD / 4 / 256, 256, 0, stream>>>(sigq, Zb, tot, Yb);

  // 7) out = Y @ Wo^T + bo  (f32), 64x128 tiles for 1024 blocks
  dim3 go(1024 / 128, 8192 / 64);
  k_gemm_out64<<<go, 256, 0, stream>>>(Yb, Wob, bo, out);
}

// Round 3
// 209.035 us; speedup vs baseline: 1.4486x; 1.1085x over previous
//
#include <hip/hip_runtime.h>
#include <hip/hip_bf16.h>
#include <cstdint>

// AFT-Local, S=2048 B=4 D=1024 W=256.
// num/den softmax normalizers cancel; exp_pb = 1 + c (c=expm1(pos_bias) inside window j<=i-255, else 0)
//  => num = colsum(U) + C@U, den = colsum(E) + C@E, with U=exp(k)*v, E=exp(k).
// Mt stores U/E column-major interleaved at 16-row granularity:
//   Mt row r = 32*(n>>4) + (n&15) + 16*isE   (n = b*1024+d)
// so the tri-GEMM's even/odd 16-col fragments hold matching (Zu, Ze) for the same n,
// letting the epilogue compute y = sigmoid(q)*(tu+Zu)/(te+Ze) in-register (k_y fused away).
// mask input (d_in[12]) is all-True -> no-op in the reference; ignored here.

typedef short short8 __attribute__((ext_vector_type(8)));
typedef float f32x4 __attribute__((ext_vector_type(4)));

#define S_LEN 2048
#define NBD 4096           // B*D
#define SBD 8388608        // S*B*D
#define DD 1048576         // D*D
#define SS 4194304         // S*S

__device__ __forceinline__ unsigned short f2bf(float f) {
  union { float f; unsigned int u; } x; x.f = f;
  unsigned int u = x.u;
  unsigned int r = u + 0x7fffu + ((u >> 16) & 1u);
  return (unsigned short)(r >> 16);
}
__device__ __forceinline__ float bf2f(unsigned short b) {
  union { unsigned int u; float f; } x; x.u = ((unsigned int)b) << 16;
  return x.f;
}

// ---------------- fused f32 -> bf16 converts ----------------
__global__ void k_cvt3(const float* __restrict__ a, const float* __restrict__ b,
                       const float* __restrict__ c, unsigned short* __restrict__ oa,
                       unsigned short* __restrict__ ob, unsigned short* __restrict__ oc) {
  int i = (blockIdx.x * blockDim.x + threadIdx.x) * 4;  // over SBD
  float4 fa = *(const float4*)(a + i);
  float4 fb = *(const float4*)(b + i);
  float4 fc = *(const float4*)(c + i);
  ushort4 ua, ub, uc;
  ua.x = f2bf(fa.x); ua.y = f2bf(fa.y); ua.z = f2bf(fa.z); ua.w = f2bf(fa.w);
  ub.x = f2bf(fb.x); ub.y = f2bf(fb.y); ub.z = f2bf(fb.z); ub.w = f2bf(fb.w);
  uc.x = f2bf(fc.x); uc.y = f2bf(fc.y); uc.z = f2bf(fc.z); uc.w = f2bf(fc.w);
  *(ushort4*)(oa + i) = ua;
  *(ushort4*)(ob + i) = ub;
  *(ushort4*)(oc + i) = uc;
}

__global__ void k_cvt4w(const float* __restrict__ wq, const float* __restrict__ wk,
                        const float* __restrict__ wv, const float* __restrict__ wo,
                        unsigned short* __restrict__ wcat, unsigned short* __restrict__ wob) {
  int i = (blockIdx.x * blockDim.x + threadIdx.x) * 4;  // over DD
  float4 fq = *(const float4*)(wq + i);
  float4 fk = *(const float4*)(wk + i);
  float4 fv = *(const float4*)(wv + i);
  float4 fo = *(const float4*)(wo + i);
  ushort4 u;
  u.x = f2bf(fq.x); u.y = f2bf(fq.y); u.z = f2bf(fq.z); u.w = f2bf(fq.w);
  *(ushort4*)(wcat + i) = u;
  u.x = f2bf(fk.x); u.y = f2bf(fk.y); u.z = f2bf(fk.z); u.w = f2bf(fk.w);
  *(ushort4*)(wcat + DD + i) = u;
  u.x = f2bf(fv.x); u.y = f2bf(fv.y); u.z = f2bf(fv.z); u.w = f2bf(fv.w);
  *(ushort4*)(wcat + 2 * DD + i) = u;
  u.x = f2bf(fo.x); u.y = f2bf(fo.y); u.z = f2bf(fo.z); u.w = f2bf(fo.w);
  *(ushort4*)(wob + i) = u;
}

// ---------------- C[i][j] = (i >= j+255) ? expm1(pos_bias) : 0 ----------------
__global__ void k_build_c(const float* __restrict__ pb, unsigned short* __restrict__ C) {
  int idx = blockIdx.x * blockDim.x + threadIdx.x;  // over S*S
  int i = idx >> 11;
  int j = idx & 2047;
  float v = (i >= j + 255) ? expm1f(pb[idx]) : 0.0f;
  C[idx] = f2bf(v);
}

// ---------------- E/U compute + transpose into interleaved Mt + column totals ----------------
__global__ __launch_bounds__(256) void k_eu_transpose(
    const unsigned short* __restrict__ kbf, const unsigned short* __restrict__ vbf,
    unsigned short* __restrict__ Mt, float* __restrict__ totals) {
  __shared__ unsigned short Lu[64][65];
  __shared__ unsigned short Le[64][65];
  const int n0 = blockIdx.x * 64;
  const int j0 = blockIdx.y * 64;
  const int t = threadIdx.x;
  const int c = t & 63;
  const int jq = t >> 6;
  float ptu = 0.f, pte = 0.f;
#pragma unroll 4
  for (int s = 0; s < 16; ++s) {
    int jj = jq + s * 4;
    size_t g = (size_t)(j0 + jj) * NBD + n0 + c;
    float kv = bf2f(kbf[g]);
    float vv = bf2f(vbf[g]);
    float e = __expf(kv);
    float u = e * vv;
    Le[jj][c] = f2bf(e);
    Lu[jj][c] = f2bf(u);
    pte += e; ptu += u;
  }
  atomicAdd(&totals[n0 + c], ptu);
  atomicAdd(&totals[NBD + n0 + c], pte);
  __syncthreads();
  const int jj2 = t & 63;
  const int nq = t >> 6;
#pragma unroll 4
  for (int s = 0; s < 16; ++s) {
    int nn = nq + s * 4;
    // interleaved row: ru = 2*n0 + 32*(nn>>4) + (nn&15); E rows at +16
    int ru = 2 * n0 + 32 * (nn >> 4) + (nn & 15);
    Mt[(size_t)ru * S_LEN + j0 + jj2] = Lu[jj2][nn];
    Mt[(size_t)(ru + 16) * S_LEN + j0 + jj2] = Le[jj2][nn];
  }
}

// ---------------- fused QKV GEMM, XCD-swizzled 1D grid (1536 blocks) ----------------
__global__ __launch_bounds__(256) void k_gemm_qkv(
    const unsigned short* __restrict__ A0, const unsigned short* __restrict__ A1,
    const unsigned short* __restrict__ A2, const unsigned short* __restrict__ Wcat,
    const float* __restrict__ b0, const float* __restrict__ b1, const float* __restrict__ b2,
    unsigned short* __restrict__ o0, unsigned short* __restrict__ o1,
    unsigned short* __restrict__ o2) {
  __shared__ __align__(16) unsigned short lab[128 * 32];
  __shared__ __align__(16) unsigned short lbb[128 * 32];
  const int tid = threadIdx.x;
  const int wave = tid >> 6, lane = tid & 63;
  // XCD-locality remap: each XCD owns 8 consecutive mb rows, nb fastest
  const int w = blockIdx.x;
  const int xcd = w & 7, slot = w >> 3;      // slot 0..191
  const int mb = xcd * 8 + slot / 24;
  const int nb = slot % 24;
  const int m0 = mb * 128, n0 = nb * 128;
  const int grp = nb >> 3;  // 0=q, 1=k, 2=v
  const unsigned short* A = grp == 0 ? A0 : (grp == 1 ? A1 : A2);
  const float* bias = grp == 0 ? b0 : (grp == 1 ? b1 : b2);
  unsigned short* out = grp == 0 ? o0 : (grp == 1 ? o1 : o2);
  const int l15 = lane & 15, lh = lane >> 4;
  const int wr = (wave >> 1) * 64, wc = (wave & 1) * 64;

  f32x4 acc[4][4];
#pragma unroll
  for (int i = 0; i < 4; ++i)
#pragma unroll
    for (int j = 0; j < 4; ++j)
      acc[i][j] = (f32x4){0.f, 0.f, 0.f, 0.f};

  const int srow = lane >> 2;
  const int scol = (lane & 3) * 8;

  for (int kt = 0; kt < 32; ++kt) {
    const int k0 = kt * 32;
    if (kt) __syncthreads();
#pragma unroll
    for (int cdx = 0; cdx < 2; ++cdx) {
      const int seg = wave * 2 + cdx;
      const int row = seg * 16 + srow;
      __builtin_amdgcn_global_load_lds(
          (const __attribute__((address_space(1))) unsigned int*)(A + (size_t)(m0 + row) * 1024 + k0 + scol),
          (__attribute__((address_space(3))) unsigned int*)&lab[seg * 512], 16, 0, 0);
      __builtin_amdgcn_global_load_lds(
          (const __attribute__((address_space(1))) unsigned int*)(Wcat + (size_t)(n0 + row) * 1024 + k0 + scol),
          (__attribute__((address_space(3))) unsigned int*)&lbb[seg * 512], 16, 0, 0);
    }
    __syncthreads();
    short8 af[4], bfr[4];
#pragma unroll
    for (int f = 0; f < 4; ++f)
      af[f] = *(const short8*)&lab[(wr + f * 16 + l15) * 32 + lh * 8];
#pragma unroll
    for (int f = 0; f < 4; ++f)
      bfr[f] = *(const short8*)&lbb[(wc + f * 16 + l15) * 32 + lh * 8];
#pragma unroll
    for (int i = 0; i < 4; ++i)
#pragma unroll
      for (int j = 0; j < 4; ++j)
        acc[i][j] = __builtin_amdgcn_mfma_f32_16x16x32_bf16(af[i], bfr[j], acc[i][j], 0, 0, 0);
  }

#pragma unroll
  for (int i = 0; i < 4; ++i)
#pragma unroll
    for (int j = 0; j < 4; ++j)
#pragma unroll
      for (int r = 0; r < 4; ++r) {
        const int row = m0 + wr + i * 16 + lh * 4 + r;
        const int col = (n0 + wc + j * 16 + l15) & 1023;
        float v = acc[i][j][r] + bias[col];
        if (grp == 0) v = 1.0f / (1.0f + __expf(-v));
        out[(size_t)row * 1024 + col] = f2bf(v);
      }
}

// ---------------- triangular Z = C @ Mt-rows, fused y epilogue, heavy-first ----------------
__global__ __launch_bounds__(256) void k_gemm_tri(
    const unsigned short* __restrict__ A, const unsigned short* __restrict__ Bt,
    const unsigned short* __restrict__ sigq, const float* __restrict__ totals,
    unsigned short* __restrict__ Y) {
  __shared__ __align__(16) unsigned short lab[128 * 32];
  __shared__ __align__(16) unsigned short lbb[128 * 32];
  const int tid = threadIdx.x;
  const int wave = tid >> 6, lane = tid & 63;
  // heavy-first: mb descending so 57-k-tile blocks dispatch first
  const int w = blockIdx.x;           // 0..1023
  const int mb = 15 - (w >> 6);
  const int nb = w & 63;
  const int m0 = mb * 128, n0 = nb * 128;
  const int l15 = lane & 15, lh = lane >> 4;
  const int wr = (wave >> 1) * 64, wc = (wave & 1) * 64;

  f32x4 acc[4][4];
#pragma unroll
  for (int i = 0; i < 4; ++i)
#pragma unroll
    for (int j = 0; j < 4; ++j)
      acc[i][j] = (f32x4){0.f, 0.f, 0.f, 0.f};

  // window j <= i-255: nonzero k-tiles are 0 .. 4*mb-4
  const int nk = mb > 0 ? 4 * mb - 3 : 0;
  const int srow = lane >> 2;
  const int scol = (lane & 3) * 8;

  for (int kt = 0; kt < nk; ++kt) {
    const int k0 = kt * 32;
    if (kt) __syncthreads();
#pragma unroll
    for (int cdx = 0; cdx < 2; ++cdx) {
      const int seg = wave * 2 + cdx;
      const int row = seg * 16 + srow;
      __builtin_amdgcn_global_load_lds(
          (const __attribute__((address_space(1))) unsigned int*)(A + (size_t)(m0 + row) * S_LEN + k0 + scol),
          (__attribute__((address_space(3))) unsigned int*)&lab[seg * 512], 16, 0, 0);
      __builtin_amdgcn_global_load_lds(
          (const __attribute__((address_space(1))) unsigned int*)(Bt + (size_t)(n0 + row) * S_LEN + k0 + scol),
          (__attribute__((address_space(3))) unsigned int*)&lbb[seg * 512], 16, 0, 0);
    }
    __syncthreads();
    short8 af[4], bfr[4];
#pragma unroll
    for (int f = 0; f < 4; ++f)
      af[f] = *(const short8*)&lab[(wr + f * 16 + l15) * 32 + lh * 8];
#pragma unroll
    for (int f = 0; f < 4; ++f)
      bfr[f] = *(const short8*)&lbb[(wc + f * 16 + l15) * 32 + lh * 8];
#pragma unroll
    for (int i = 0; i < 4; ++i)
#pragma unroll
      for (int j = 0; j < 4; ++j)
        acc[i][j] = __builtin_amdgcn_mfma_f32_16x16x32_bf16(af[i], bfr[j], acc[i][j], 0, 0, 0);
  }

  // fused epilogue: even frag j holds Zu, odd frag j holds Ze for the SAME n
  // n = 64*nb + (2*(wave&1) + p)*16 + l15, rows = sequence positions
#pragma unroll
  for (int i = 0; i < 4; ++i)
#pragma unroll
    for (int p = 0; p < 2; ++p) {
      const int n = 64 * nb + (2 * (wave & 1) + p) * 16 + l15;
      const float tu = totals[n];
      const float te = totals[NBD + n];
#pragma unroll
      for (int r = 0; r < 4; ++r) {
        const int row = m0 + wr + i * 16 + lh * 4 + r;
        const size_t idx = (size_t)row * NBD + n;
        const float num = tu + acc[i][2 * p][r];
        const float den = te + acc[i][2 * p + 1][r];
        Y[idx] = f2bf(bf2f(sigq[idx]) * num / den);
      }
    }
}

// ---------------- output GEMM: out = Y @ Wo^T + bo, 64x128 tile, XCD-swizzled ----------------
__global__ __launch_bounds__(256) void k_gemm_out64(
    const unsigned short* __restrict__ A, const unsigned short* __restrict__ Bt,
    const float* __restrict__ bias, float* __restrict__ out) {
  __shared__ __align__(16) unsigned short laa[64 * 32];
  __shared__ __align__(16) unsigned short lbb[128 * 32];
  const int tid = threadIdx.x;
  const int wave = tid >> 6, lane = tid & 63;
  // XCD-locality remap: each XCD owns 16 consecutive mb rows, nb fastest
  const int w = blockIdx.x;                  // 0..1023
  const int xcd = w & 7, slot = w >> 3;      // slot 0..127
  const int mb = xcd * 16 + (slot >> 3);
  const int nb = slot & 7;
  const int m0 = mb * 64, n0 = nb * 128;
  const int l15 = lane & 15, lh = lane >> 4;
  const int wr = (wave >> 1) * 32, wc = (wave & 1) * 64;

  f32x4 acc[2][4];
#pragma unroll
  for (int i = 0; i < 2; ++i)
#pragma unroll
    for (int j = 0; j < 4; ++j)
      acc[i][j] = (f32x4){0.f, 0.f, 0.f, 0.f};

  const int srow = lane >> 2;
  const int scol = (lane & 3) * 8;

  for (int kt = 0; kt < 32; ++kt) {
    const int k0 = kt * 32;
    if (kt) __syncthreads();
    {
      const int row = wave * 16 + srow;
      __builtin_amdgcn_global_load_lds(
          (const __attribute__((address_space(1))) unsigned int*)(A + (size_t)(m0 + row) * 1024 + k0 + scol),
          (__attribute__((address_space(3))) unsigned int*)&laa[wave * 512], 16, 0, 0);
    }
#pragma unroll
    for (int cdx = 0; cdx < 2; ++cdx) {
      const int seg = wave * 2 + cdx;
      const int row = seg * 16 + srow;
      __builtin_amdgcn_global_load_lds(
          (const __attribute__((address_space(1))) unsigned int*)(Bt + (size_t)(n0 + row) * 1024 + k0 + scol),
          (__attribute__((address_space(3))) unsigned int*)&lbb[seg * 512], 16, 0, 0);
    }
    __syncthreads();
    short8 af[2], bfr[4];
#pragma unroll
    for (int f = 0; f < 2; ++f)
      af[f] = *(const short8*)&laa[(wr + f * 16 + l15) * 32 + lh * 8];
#pragma unroll
    for (int f = 0; f < 4; ++f)
      bfr[f] = *(const short8*)&lbb[(wc + f * 16 + l15) * 32 + lh * 8];
#pragma unroll
    for (int i = 0; i < 2; ++i)
#pragma unroll
      for (int j = 0; j < 4; ++j)
        acc[i][j] = __builtin_amdgcn_mfma_f32_16x16x32_bf16(af[i], bfr[j], acc[i][j], 0, 0, 0);
  }

#pragma unroll
  for (int i = 0; i < 2; ++i)
#pragma unroll
    for (int j = 0; j < 4; ++j)
#pragma unroll
      for (int r = 0; r < 4; ++r) {
        const int row = m0 + wr + i * 16 + lh * 4 + r;
        const int col = n0 + wc + j * 16 + l15;
        out[(size_t)row * 1024 + col] = acc[i][j][r] + bias[col];
      }
}

extern "C" void kernel_launch(void* const* d_in, const int* in_sizes, int n_in,
                              void* d_out, int out_size, void* d_ws, size_t ws_size,
                              hipStream_t stream) {
  const float* query   = (const float*)d_in[0];
  const float* key_in  = (const float*)d_in[1];
  const float* value   = (const float*)d_in[2];
  const float* Wq      = (const float*)d_in[3];
  const float* bq      = (const float*)d_in[4];
  const float* Wk      = (const float*)d_in[5];
  const float* bk      = (const float*)d_in[6];
  const float* Wv      = (const float*)d_in[7];
  const float* bv      = (const float*)d_in[8];
  const float* pos_bias= (const float*)d_in[9];
  const float* Wo      = (const float*)d_in[10];
  const float* bo      = (const float*)d_in[11];
  float* out = (float*)d_out;

  char* wp = (char*)d_ws;
  auto alloc = [&](size_t bytes) -> char* {
    char* p = wp;
    wp += (bytes + 255) & ~(size_t)255;
    return p;
  };
  unsigned short* Xq   = (unsigned short*)alloc((size_t)SBD * 2);
  unsigned short* Xk   = (unsigned short*)alloc((size_t)SBD * 2);
  unsigned short* Xv   = (unsigned short*)alloc((size_t)SBD * 2);
  unsigned short* Wcat = (unsigned short*)alloc((size_t)3 * DD * 2);
  unsigned short* Wob  = (unsigned short*)alloc((size_t)DD * 2);
  unsigned short* Cb   = (unsigned short*)alloc((size_t)SS * 2);
  unsigned short* sigq = (unsigned short*)alloc((size_t)SBD * 2);
  unsigned short* kbf  = (unsigned short*)alloc((size_t)SBD * 2);
  unsigned short* vbf  = (unsigned short*)alloc((size_t)SBD * 2);
  unsigned short* Mt   = (unsigned short*)alloc((size_t)8192 * S_LEN * 2);
  float*          tot  = (float*)alloc((size_t)8192 * 4);
  unsigned short* Yb   = (unsigned short*)alloc((size_t)SBD * 2);

  // 1) converts
  k_cvt3<<<SBD / 4 / 256, 256, 0, stream>>>(query, key_in, value, Xq, Xk, Xv);
  k_cvt4w<<<DD / 4 / 256, 256, 0, stream>>>(Wq, Wk, Wv, Wo, Wcat, Wob);

  // 2) windowed expm1 coefficient matrix
  k_build_c<<<SS / 256, 256, 0, stream>>>(pos_bias, Cb);

  // 3) fused QKV projection  [8192,1024]x3 @ [3072,1024]^T  (1536 blocks, XCD-swizzled)
  k_gemm_qkv<<<1536, 256, 0, stream>>>(Xq, Xk, Xv, Wcat, bq, bk, bv, sigq, kbf, vbf);

  // 4) E/U + interleaved transpose + totals
  hipMemsetAsync(tot, 0, 8192 * sizeof(float), stream);
  dim3 ge(NBD / 64, S_LEN / 64);
  k_eu_transpose<<<ge, 256, 0, stream>>>(kbf, vbf, Mt, tot);

  // 5) tri GEMM + fused y epilogue  (1024 blocks, heavy-first)
  k_gemm_tri<<<1024, 256, 0, stream>>>(Cb, Mt, sigq, tot, Yb);

  // 6) out = Y @ Wo^T + bo  (f32), 64x128 tiles, XCD-swizzled
  k_gemm_out64<<<1024, 256, 0, stream>>>(Yb, Wob, bo, out);
}

// Round 4
// 179.623 us; speedup vs baseline: 1.6858x; 1.1637x over previous
//
#include <hip/hip_runtime.h>
#include <hip/hip_bf16.h>
#include <cstdint>

// AFT-Local, S=2048 B=4 D=1024 W=256.
// num/den softmax normalizers cancel; exp_pb = 1 + c (c=expm1(pos_bias) inside window j<=i-255, else 0)
//  => num = colsum(U) + C@U, den = colsum(E) + C@E, with U=exp(k)*v, E=exp(k).
// Mt stores U/E column-major interleaved at 16-row granularity:
//   Mt row r = 32*(n>>4) + (n&15) + 16*isE   (n = b*1024+d)
// so the tri-GEMM's even/odd 16-col fragments hold matching (Zu, Ze) for the same n.
// mask input (d_in[12]) is all-True -> no-op in the reference; ignored here.
//
// GEMM template: BM=128, BN=256, BK=64, 8 waves (2Mx4N, 64x64 per wave), 512 thr.
// Triple-buffered LDS (3 x 48KB = 144KB), counted vmcnt(6) (never 0 mid-loop),
// raw s_barrier + sched_barrier(0), T2 XOR-swizzle (both sides), T5 setprio.

typedef short short8 __attribute__((ext_vector_type(8)));
typedef float f32x4 __attribute__((ext_vector_type(4)));

#define S_LEN 2048
#define NBD 4096           // B*D
#define SBD 8388608        // S*B*D
#define DD 1048576         // D*D
#define SS 4194304         // S*S

#define ASZ 8192           // A region elems: 128*64
#define BUFSZ 24576        // (128+256)*64 elems per buffer
#define AS1 __attribute__((address_space(1)))
#define AS3 __attribute__((address_space(3)))

__device__ __forceinline__ unsigned short f2bf(float f) {
  union { float f; unsigned int u; } x; x.f = f;
  unsigned int u = x.u;
  unsigned int r = u + 0x7fffu + ((u >> 16) & 1u);
  return (unsigned short)(r >> 16);
}
__device__ __forceinline__ float bf2f(unsigned short b) {
  union { unsigned int u; float f; } x; x.u = ((unsigned int)b) << 16;
  return x.f;
}

// ---------------- fused f32 -> bf16 converts ----------------
__global__ void k_cvt3(const float* __restrict__ a, const float* __restrict__ b,
                       const float* __restrict__ c, unsigned short* __restrict__ oa,
                       unsigned short* __restrict__ ob, unsigned short* __restrict__ oc) {
  int i = (blockIdx.x * blockDim.x + threadIdx.x) * 4;  // over SBD
  float4 fa = *(const float4*)(a + i);
  float4 fb = *(const float4*)(b + i);
  float4 fc = *(const float4*)(c + i);
  ushort4 ua, ub, uc;
  ua.x = f2bf(fa.x); ua.y = f2bf(fa.y); ua.z = f2bf(fa.z); ua.w = f2bf(fa.w);
  ub.x = f2bf(fb.x); ub.y = f2bf(fb.y); ub.z = f2bf(fb.z); ub.w = f2bf(fb.w);
  uc.x = f2bf(fc.x); uc.y = f2bf(fc.y); uc.z = f2bf(fc.z); uc.w = f2bf(fc.w);
  *(ushort4*)(oa + i) = ua;
  *(ushort4*)(ob + i) = ub;
  *(ushort4*)(oc + i) = uc;
}

__global__ void k_cvt4w(const float* __restrict__ wq, const float* __restrict__ wk,
                        const float* __restrict__ wv, const float* __restrict__ wo,
                        unsigned short* __restrict__ wcat, unsigned short* __restrict__ wob) {
  int i = (blockIdx.x * blockDim.x + threadIdx.x) * 4;  // over DD
  float4 fq = *(const float4*)(wq + i);
  float4 fk = *(const float4*)(wk + i);
  float4 fv = *(const float4*)(wv + i);
  float4 fo = *(const float4*)(wo + i);
  ushort4 u;
  u.x = f2bf(fq.x); u.y = f2bf(fq.y); u.z = f2bf(fq.z); u.w = f2bf(fq.w);
  *(ushort4*)(wcat + i) = u;
  u.x = f2bf(fk.x); u.y = f2bf(fk.y); u.z = f2bf(fk.z); u.w = f2bf(fk.w);
  *(ushort4*)(wcat + DD + i) = u;
  u.x = f2bf(fv.x); u.y = f2bf(fv.y); u.z = f2bf(fv.z); u.w = f2bf(fv.w);
  *(ushort4*)(wcat + 2 * DD + i) = u;
  u.x = f2bf(fo.x); u.y = f2bf(fo.y); u.z = f2bf(fo.z); u.w = f2bf(fo.w);
  *(ushort4*)(wob + i) = u;
}

// ---------------- C[i][j] = (i >= j+255) ? expm1(pos_bias) : 0 ----------------
__global__ void k_build_c(const float* __restrict__ pb, unsigned short* __restrict__ C) {
  int idx = blockIdx.x * blockDim.x + threadIdx.x;  // over S*S
  int i = idx >> 11;
  int j = idx & 2047;
  float v = (i >= j + 255) ? expm1f(pb[idx]) : 0.0f;
  C[idx] = f2bf(v);
}

// ---------------- E/U compute + transpose into interleaved Mt + column totals ----------------
__global__ __launch_bounds__(256) void k_eu_transpose(
    const unsigned short* __restrict__ kbf, const unsigned short* __restrict__ vbf,
    unsigned short* __restrict__ Mt, float* __restrict__ totals) {
  __shared__ unsigned short Lu[64][65];
  __shared__ unsigned short Le[64][65];
  const int n0 = blockIdx.x * 64;
  const int j0 = blockIdx.y * 64;
  const int t = threadIdx.x;
  const int c = t & 63;
  const int jq = t >> 6;
  float ptu = 0.f, pte = 0.f;
#pragma unroll 4
  for (int s = 0; s < 16; ++s) {
    int jj = jq + s * 4;
    size_t g = (size_t)(j0 + jj) * NBD + n0 + c;
    float kv = bf2f(kbf[g]);
    float vv = bf2f(vbf[g]);
    float e = __expf(kv);
    float u = e * vv;
    Le[jj][c] = f2bf(e);
    Lu[jj][c] = f2bf(u);
    pte += e; ptu += u;
  }
  atomicAdd(&totals[n0 + c], ptu);
  atomicAdd(&totals[NBD + n0 + c], pte);
  __syncthreads();
  const int jj2 = t & 63;
  const int nq = t >> 6;
#pragma unroll 4
  for (int s = 0; s < 16; ++s) {
    int nn = nq + s * 4;
    int ru = 2 * n0 + 32 * (nn >> 4) + (nn & 15);
    Mt[(size_t)ru * S_LEN + j0 + jj2] = Lu[jj2][nn];
    Mt[(size_t)(ru + 16) * S_LEN + j0 + jj2] = Le[jj2][nn];
  }
}

// ================= pipelined GEMM template =================
// MODE 0: qkv   A(grp-sel Xq/Xk/Xv)[8192,1024] @ Wcat[3072,1024]^T, bias(+sigmoid grp0) -> bf16
// MODE 1: tri   Cb[2048,2048] @ Mt[8192,2048]^T (lower-block-tri), fused y epilogue -> bf16
// MODE 2: out   Yb[8192,1024] @ Wob[1024,1024]^T + bo -> f32

#define SBAR() do { __builtin_amdgcn_sched_barrier(0); __builtin_amdgcn_s_barrier(); \
                    __builtin_amdgcn_sched_barrier(0); } while (0)
#define VM(n)  do { asm volatile("s_waitcnt vmcnt(" #n ")" ::: "memory"); \
                    __builtin_amdgcn_sched_barrier(0); } while (0)
#define LGK0() do { asm volatile("s_waitcnt lgkmcnt(0)" ::: "memory"); \
                    __builtin_amdgcn_sched_barrier(0); } while (0)

#define STAGE(tile, bidx) do {                                                            \
    const int k0s_ = (tile) * 64;                                                         \
    _Pragma("unroll") for (int q_ = 0; q_ < 2; ++q_) {                                    \
      const int g_ = wave * 2 + q_;                                                       \
      __builtin_amdgcn_global_load_lds(                                                   \
          (const AS1 unsigned int*)(Ag + (size_t)(m0 + g_ * 8 + lr) * LDA + k0s_ + lc),   \
          (AS3 unsigned int*)&lds[(bidx) * BUFSZ + g_ * 512], 16, 0, 0);                  \
    }                                                                                     \
    _Pragma("unroll") for (int q_ = 0; q_ < 4; ++q_) {                                    \
      const int g_ = wave * 4 + q_;                                                       \
      __builtin_amdgcn_global_load_lds(                                                   \
          (const AS1 unsigned int*)(Bg + (size_t)(n0 + g_ * 8 + lr) * LDB + k0s_ + lc),   \
          (AS3 unsigned int*)&lds[(bidx) * BUFSZ + ASZ + g_ * 512], 16, 0, 0);            \
    }                                                                                     \
  } while (0)

#define READF(RA, RB, bidx, ks) do {                                                      \
    const int kof_ = (ks) * 32 + lh8;                                                     \
    _Pragma("unroll") for (int f_ = 0; f_ < 4; ++f_) {                                    \
      const int row_ = wr + f_ * 16 + l15;                                                \
      RA[f_] = *(const short8*)&lds[(bidx) * BUFSZ + row_ * 64 + (kof_ ^ swz)];           \
    }                                                                                     \
    _Pragma("unroll") for (int f_ = 0; f_ < 4; ++f_) {                                    \
      const int row_ = wc + f_ * 16 + l15;                                                \
      RB[f_] = *(const short8*)&lds[(bidx) * BUFSZ + ASZ + row_ * 64 + (kof_ ^ swz)];     \
    }                                                                                     \
  } while (0)

#define MFMA16(RA, RB) do {                                                               \
    __builtin_amdgcn_s_setprio(1);                                                        \
    _Pragma("unroll") for (int i_ = 0; i_ < 4; ++i_)                                      \
    _Pragma("unroll") for (int j_ = 0; j_ < 4; ++j_)                                      \
      acc[i_][j_] = __builtin_amdgcn_mfma_f32_16x16x32_bf16(RA[i_], RB[j_],               \
                                                            acc[i_][j_], 0, 0, 0);       \
    __builtin_amdgcn_s_setprio(0);                                                        \
  } while (0)

template <int MODE>
__global__ __launch_bounds__(512, 2) void k_gemm8(
    const unsigned short* __restrict__ A0, const unsigned short* __restrict__ A1,
    const unsigned short* __restrict__ A2, const unsigned short* __restrict__ Bg,
    const float* __restrict__ x0, const float* __restrict__ x1, const float* __restrict__ x2,
    const unsigned short* __restrict__ sq,
    void* __restrict__ out0, void* __restrict__ out1, void* __restrict__ out2) {
  __shared__ unsigned short lds[3 * BUFSZ];  // 144 KB

  const int tid = threadIdx.x;
  const int wave = tid >> 6, lane = tid & 63;
  const int l15 = lane & 15, lh = lane >> 4;
  const int lh8 = lh * 8;
  const int swz = (l15 & 7) * 8;             // read-side XOR (elements)
  const int lr = lane >> 3;                  // stage: row within 8-row group
  const int lc = ((lane & 7) ^ lr) * 8;      // stage: pre-swizzled global col (elements)
  const int wr = (wave >> 2) * 64, wc = (wave & 3) * 64;

  const int w = blockIdx.x;
  int mb, nb;
  if (MODE == 0) { const int xcd = w & 7, slot = w >> 3; mb = xcd * 8 + slot / 12; nb = slot % 12; }
  else if (MODE == 1) { mb = 15 - (w >> 5); nb = w & 31; }
  else { const int xcd = w & 7, slot = w >> 3; mb = xcd * 8 + (slot >> 2); nb = slot & 3; }
  const int m0 = mb * 128, n0 = nb * 256;
  const int LDA = (MODE == 1) ? 2048 : 1024;
  const int LDB = (MODE == 1) ? 2048 : 1024;
  const int NT = (MODE == 1) ? (mb > 0 ? 2 * mb - 1 : 0) : 16;
  const int grp = (MODE == 0) ? (nb >> 2) : 0;
  const unsigned short* Ag = (MODE == 0) ? (grp == 0 ? A0 : (grp == 1 ? A1 : A2)) : A0;

  f32x4 acc[4][4];
#pragma unroll
  for (int i = 0; i < 4; ++i)
#pragma unroll
    for (int j = 0; j < 4; ++j)
      acc[i][j] = (f32x4){0.f, 0.f, 0.f, 0.f};

  short8 ra0[4], rb0[4], ra1[4], rb1[4];

  if (NT > 0) {
    STAGE(0, 0);
    if (NT > 1) STAGE(1, 1);
    if (NT > 2) STAGE(2, 2);
    if (NT > 2) VM(12); else if (NT > 1) VM(6); else VM(0);
    SBAR();
    READF(ra0, rb0, 0, 0);
    int cb = 0;
    for (int t = 0; t < NT; ++t) {
      // phase A (k-step 0 of tile t): prefetch ks1 frags, compute ks0
      READF(ra1, rb1, cb, 1);
      MFMA16(ra0, rb0);
      if (t < NT - 1) {
        // phase B: cross into tile t+1; keep stage(t+2) in flight (counted vmcnt)
        LGK0();                               // all reads of buf[cb] complete (this wave)
        if (t + 2 <= NT - 1) VM(6); else VM(0);
        SBAR();                               // tile t+1 staged for ALL waves; buf[cb] dead
        int nbuf = cb + 1; if (nbuf == 3) nbuf = 0;
        READF(ra0, rb0, nbuf, 0);
        if (t + 3 <= NT - 1) STAGE(t + 3, cb);
        cb = nbuf;
        MFMA16(ra1, rb1);
      } else {
        MFMA16(ra1, rb1);
      }
    }
  }

  // ---------------- epilogues ----------------
  if (MODE == 0) {
    const float* bias = grp == 0 ? x0 : (grp == 1 ? x1 : x2);
    unsigned short* outp = (unsigned short*)(grp == 0 ? out0 : (grp == 1 ? out1 : out2));
#pragma unroll
    for (int i = 0; i < 4; ++i)
#pragma unroll
      for (int j = 0; j < 4; ++j)
#pragma unroll
        for (int r = 0; r < 4; ++r) {
          const int row = m0 + wr + i * 16 + lh * 4 + r;
          const int col = (n0 + wc + j * 16 + l15) & 1023;
          float v = acc[i][j][r] + bias[col];
          if (grp == 0) v = 1.0f / (1.0f + __expf(-v));
          outp[(size_t)row * 1024 + col] = f2bf(v);
        }
  } else if (MODE == 1) {
    unsigned short* Y = (unsigned short*)out0;
#pragma unroll
    for (int i = 0; i < 4; ++i)
#pragma unroll
      for (int p = 0; p < 2; ++p) {
        const int n = ((n0 + wc) >> 1) + 16 * p + l15;
        const float tu = x0[n];
        const float te = x0[NBD + n];
#pragma unroll
        for (int r = 0; r < 4; ++r) {
          const int row = m0 + wr + i * 16 + lh * 4 + r;
          const size_t idx = (size_t)row * NBD + n;
          const float num = tu + acc[i][2 * p][r];
          const float den = te + acc[i][2 * p + 1][r];
          Y[idx] = f2bf(bf2f(sq[idx]) * num / den);
        }
      }
  } else {
    float* outp = (float*)out0;
#pragma unroll
    for (int i = 0; i < 4; ++i)
#pragma unroll
      for (int j = 0; j < 4; ++j)
#pragma unroll
        for (int r = 0; r < 4; ++r) {
          const int row = m0 + wr + i * 16 + lh * 4 + r;
          const int col = n0 + wc + j * 16 + l15;
          outp[(size_t)row * 1024 + col] = acc[i][j][r] + x0[col];
        }
  }
}

extern "C" void kernel_launch(void* const* d_in, const int* in_sizes, int n_in,
                              void* d_out, int out_size, void* d_ws, size_t ws_size,
                              hipStream_t stream) {
  const float* query   = (const float*)d_in[0];
  const float* key_in  = (const float*)d_in[1];
  const float* value   = (const float*)d_in[2];
  const float* Wq      = (const float*)d_in[3];
  const float* bq      = (const float*)d_in[4];
  const float* Wk      = (const float*)d_in[5];
  const float* bk      = (const float*)d_in[6];
  const float* Wv      = (const float*)d_in[7];
  const float* bv      = (const float*)d_in[8];
  const float* pos_bias= (const float*)d_in[9];
  const float* Wo      = (const float*)d_in[10];
  const float* bo      = (const float*)d_in[11];
  float* out = (float*)d_out;

  char* wp = (char*)d_ws;
  auto alloc = [&](size_t bytes) -> char* {
    char* p = wp;
    wp += (bytes + 255) & ~(size_t)255;
    return p;
  };
  unsigned short* Xq   = (unsigned short*)alloc((size_t)SBD * 2);
  unsigned short* Xk   = (unsigned short*)alloc((size_t)SBD * 2);
  unsigned short* Xv   = (unsigned short*)alloc((size_t)SBD * 2);
  unsigned short* Wcat = (unsigned short*)alloc((size_t)3 * DD * 2);
  unsigned short* Wob  = (unsigned short*)alloc((size_t)DD * 2);
  unsigned short* Cb   = (unsigned short*)alloc((size_t)SS * 2);
  unsigned short* sigq = (unsigned short*)alloc((size_t)SBD * 2);
  unsigned short* kbf  = (unsigned short*)alloc((size_t)SBD * 2);
  unsigned short* vbf  = (unsigned short*)alloc((size_t)SBD * 2);
  unsigned short* Mt   = (unsigned short*)alloc((size_t)8192 * S_LEN * 2);
  float*          tot  = (float*)alloc((size_t)8192 * 4);
  unsigned short* Yb   = (unsigned short*)alloc((size_t)SBD * 2);

  // 1) converts
  k_cvt3<<<SBD / 4 / 256, 256, 0, stream>>>(query, key_in, value, Xq, Xk, Xv);
  k_cvt4w<<<DD / 4 / 256, 256, 0, stream>>>(Wq, Wk, Wv, Wo, Wcat, Wob);

  // 2) windowed expm1 coefficient matrix
  k_build_c<<<SS / 256, 256, 0, stream>>>(pos_bias, Cb);

  // 3) fused QKV projection (768 blocks, 3 full CU-rounds, XCD-swizzled)
  k_gemm8<0><<<768, 512, 0, stream>>>(Xq, Xk, Xv, Wcat, bq, bk, bv, nullptr,
                                      sigq, kbf, vbf);

  // 4) E/U + interleaved transpose + totals
  hipMemsetAsync(tot, 0, 8192 * sizeof(float), stream);
  dim3 ge(NBD / 64, S_LEN / 64);
  k_eu_transpose<<<ge, 256, 0, stream>>>(kbf, vbf, Mt, tot);

  // 5) tri GEMM + fused y epilogue (512 blocks, heavy-first)
  k_gemm8<1><<<512, 512, 0, stream>>>(Cb, nullptr, nullptr, Mt, tot, nullptr, nullptr,
                                      sigq, Yb, nullptr, nullptr);

  // 6) out = Y @ Wo^T + bo (f32), 256 blocks = exactly 1/CU
  k_gemm8<2><<<256, 512, 0, stream>>>(Yb, nullptr, nullptr, Wob, bo, nullptr, nullptr,
                                      nullptr, out, nullptr, nullptr);
}